// Round 10
// baseline (589.555 us; speedup 1.0000x reference)
//
#include <hip/hip_runtime.h>
#include <hip/hip_bf16.h>

typedef __bf16 bf16_t;
typedef __attribute__((ext_vector_type(8))) __bf16 bf16x8;
typedef __attribute__((ext_vector_type(4))) float f32x4;
typedef __attribute__((ext_vector_type(16))) float f32x16;
typedef __attribute__((ext_vector_type(4))) unsigned int u32x4;

// ---------------------------------------------------------------------------
__device__ __forceinline__ void gload_lds16(const bf16_t* g, bf16_t* l) {
    __builtin_amdgcn_global_load_lds(
        (const __attribute__((address_space(1))) void*)g,
        (__attribute__((address_space(3))) void*)l,
        16, 0, 0);
}

__device__ __forceinline__ float gelu_f(float v) {
    float u = 0.7978845608028654f * (v + 0.044715f * v * v * v);
    float e = __expf(-2.f * u);
    float t = __fdividef(1.f - e, 1.f + e);   // tanh(u)
    return 0.5f * v * (1.f + t);
}

// ---------------------------------------------------------------------------
// MXFP4 quantize: one (32-block b, column n) -> 32 dequantized bf16 written
// transposed. Exact: pow2 scale, E2M1 midpoint rounding, bf16-exact values.
__device__ __forceinline__ void quant_one(const float* __restrict__ w,
                                          bf16_t* __restrict__ wt,
                                          int K, int N, int tix) {
    int n = tix % N;
    int b = tix / N;
    const float* src = w + (size_t)b * 32 * N + n;
    float v[32];
    float amax = 0.f;
#pragma unroll
    for (int i = 0; i < 32; ++i) {
        v[i] = __builtin_nontemporal_load(src + (size_t)i * N);
        amax = fmaxf(amax, fabsf(v[i]));
    }
    unsigned eb = (__float_as_uint(amax) >> 23) & 0xFF;
    float scale = __uint_as_float((eb - 2u) << 23);        // 2^(E-2)
    float inv   = __uint_as_float((256u - eb) << 23);      // 2^-(E-2)
    if (amax == 0.f) { scale = 0.f; inv = 0.f; }
    bf16_t dq[32];
#pragma unroll
    for (int i = 0; i < 32; ++i) {
        float x  = v[i] * inv;
        float ax = fabsf(x);
        float q = ax < 0.25f ? 0.0f : ax < 0.75f ? 0.5f : ax < 1.25f ? 1.0f :
                  ax < 1.75f ? 1.5f : ax < 2.5f  ? 2.0f : ax < 3.5f  ? 3.0f :
                  ax < 5.0f  ? 4.0f : 6.0f;
        float d = copysignf(q * scale, x);
        dq[i] = (bf16_t)d;
    }
    bf16_t* dst = wt + (size_t)n * K + b * 32;
#pragma unroll
    for (int j = 0; j < 4; ++j) {
        bf16x8 p;
#pragma unroll
        for (int t = 0; t < 8; ++t) p[t] = dq[j * 8 + t];
        *(bf16x8*)(dst + j * 8) = p;
    }
}

// ---------------------------------------------------------------------------
// Fused prep: [0,cvtB): inputs->bf16; [cvtB,cvtB+qupB): quantize up-weights;
// [cvtB+qupB,...): quantize down-weights.
__global__ void prep_kernel(const float* __restrict__ in, bf16_t* __restrict__ out,
                            int ncvt, int cvtB,
                            const float* __restrict__ upw, bf16_t* __restrict__ upwt,
                            int upK, int upN, int qupB,
                            const float* __restrict__ dnw, bf16_t* __restrict__ dnwt,
                            int dnK, int dnN) {
    int bid = blockIdx.x;
    if (bid < cvtB) {
        int i = (bid * blockDim.x + threadIdx.x) << 3;
        if (i >= ncvt) return;
        const f32x4* p = (const f32x4*)(in + i);
        f32x4 a = __builtin_nontemporal_load(p);
        f32x4 b = __builtin_nontemporal_load(p + 1);
        bf16x8 o;
        o[0] = (bf16_t)a[0]; o[1] = (bf16_t)a[1]; o[2] = (bf16_t)a[2]; o[3] = (bf16_t)a[3];
        o[4] = (bf16_t)b[0]; o[5] = (bf16_t)b[1]; o[6] = (bf16_t)b[2]; o[7] = (bf16_t)b[3];
        *(bf16x8*)(out + i) = o;
    } else if (bid < cvtB + qupB) {
        int tix = (bid - cvtB) * blockDim.x + threadIdx.x;
        if (tix >= (upK >> 5) * upN) return;
        quant_one(upw, upwt, upK, upN, tix);
    } else {
        int tix = (bid - cvtB - qupB) * blockDim.x + threadIdx.x;
        if (tix >= (dnK >> 5) * dnN) return;
        quant_one(dnw, dnwt, dnK, dnN, tix);
    }
}

// ---------------------------------------------------------------------------
// 256x256xBK=64 8-phase bf16 GEMM, now on v_mfma_f32_32x32x16_bf16
// (2382-2495 TF ubench vs 2075 for 16x16 -- +17% matrix rate).
// Staging / XOR swizzle / slots / vmcnt / barriers unchanged from the
// verified 16x16 version; only fragment indexing, MFMA calls, and the
// epilogue C-mapping (col=lane&31, row=(r&3)+8*(r>>2)+4*(lane>>5)) change.
#define VMW4  asm volatile("s_waitcnt vmcnt(4)" ::: "memory")
#define VMW0  asm volatile("s_waitcnt vmcnt(0)" ::: "memory")
#define BARR  asm volatile("s_barrier" ::: "memory")
#define LGKM0 asm volatile("s_waitcnt lgkmcnt(0)" ::: "memory")

#define MFMA32(A, B, C) __builtin_amdgcn_mfma_f32_32x32x16_bf16(A, B, C, 0, 0, 0)

// Phase P computes m-tile P (32 rows) of this buffer against both n-tiles.
#define PHASE(BUF, P, STAGE_STMT, TAIL_STMT)                                          \
  {                                                                                   \
    af0 = lda(BUF, P, 0); af1 = lda(BUF, P, 1);                                       \
    af2 = lda(BUF, P, 2); af3 = lda(BUF, P, 3);                                       \
    if ((P) == 0) {                                                                   \
      bf00 = ldb(BUF,0,0); bf01 = ldb(BUF,0,1); bf02 = ldb(BUF,0,2); bf03 = ldb(BUF,0,3); \
      bf10 = ldb(BUF,1,0); bf11 = ldb(BUF,1,1); bf12 = ldb(BUF,1,2); bf13 = ldb(BUF,1,3); \
    }                                                                                 \
    STAGE_STMT;                                                                       \
    BARR;                                                                             \
    LGKM0;                                                                            \
    __builtin_amdgcn_s_setprio(1);                                                    \
    acc[P][0] = MFMA32(af0, bf00, acc[P][0]);                                         \
    acc[P][1] = MFMA32(af0, bf10, acc[P][1]);                                         \
    acc[P][0] = MFMA32(af1, bf01, acc[P][0]);                                         \
    acc[P][1] = MFMA32(af1, bf11, acc[P][1]);                                         \
    acc[P][0] = MFMA32(af2, bf02, acc[P][0]);                                         \
    acc[P][1] = MFMA32(af2, bf12, acc[P][1]);                                         \
    acc[P][0] = MFMA32(af3, bf03, acc[P][0]);                                         \
    acc[P][1] = MFMA32(af3, bf13, acc[P][1]);                                         \
    __builtin_amdgcn_s_setprio(0);                                                    \
    TAIL_STMT;                                                                        \
    BARR;                                                                             \
  }

template <int EPI, int MAP>
__global__ __launch_bounds__(512, 2)
void gemm_kernel(const bf16_t* __restrict__ A, const bf16_t* __restrict__ Bt,
                 const float* __restrict__ bias, void* __restrict__ Cout,
                 int M, int N, int K) {
    __shared__ __align__(16) char smem[131072];
    bf16_t* sAp = (bf16_t*)smem;               // [2][256*64]
    bf16_t* sBp = (bf16_t*)(smem + 65536);     // [2][256*64]
    const int tid    = threadIdx.x;
    const int lane   = tid & 63;
    const int wv     = tid >> 6;           // 0..7
    const int wr     = wv >> 2;            // 0..1 (M)
    const int wc     = wv & 3;             // 0..3 (N)
    const int lane31 = lane & 31;
    const int laneHi2 = lane >> 5;         // 0..1

    int bm, bn;
    const int bid = blockIdx.x;
    if (MAP == 1) {
        // hierarchical: per-XCD concurrent window = 4bm x 8bn supertile.
        const int xcd = bid & 7;
        const int l   = bid >> 3;
        const int r   = l >> 5;
        const int u   = l & 31;
        bm = r * 8 + ((xcd >> 2) << 2) + (u >> 3);
        bn = ((xcd & 3) << 3) + (u & 7);
    } else {
        const int ntn = N >> 8;
        const int nwg = gridDim.x;
        int wg  = (bid & 7) * (nwg >> 3) + (bid >> 3);
        bm = wg / ntn; bn = wg % ntn;
    }

    // --- staging (unchanged): wave covers 8 rows x 64 cols per instr ---
    const int sr8 = lane >> 3;
    const int swz = (((lane & 7) ^ sr8) << 3);
    const bf16_t* aSrc = A  + (size_t)(bm * 256 + wv * 8 + sr8) * K + swz;
    const bf16_t* bSrc = Bt + (size_t)(bn * 256 + wv * 8 + sr8) * K + swz;

    auto stageA = [&](int b, int kt, int h) {
        const bf16_t* s = aSrc + (size_t)(h * 128) * K + kt * 64;
        gload_lds16(s,                &sAp[b * 16384 + (h * 128 + wv * 8) * 64]);
        gload_lds16(s + (size_t)64*K, &sAp[b * 16384 + (h * 128 + 64 + wv * 8) * 64]);
    };
    auto stageB = [&](int b, int kt, int h) {
        const bf16_t* s = bSrc + (size_t)(h * 128) * K + kt * 64;
        gload_lds16(s,                &sBp[b * 16384 + (h * 128 + wv * 8) * 64]);
        gload_lds16(s + (size_t)64*K, &sBp[b * 16384 + (h * 128 + 64 + wv * 8) * 64]);
    };

    // --- 32x32 fragment reads: row = lane&31, k-unit u_log = 2k + (lane>>5),
    //     u_phys = u_log ^ (row&7) (same involution as the staging swizzle) ---
    const int s7 = lane31 & 7;
    auto lda = [&](int b, int mt, int k) -> bf16x8 {
        const int row = wr * 128 + mt * 32 + lane31;
        const int up  = ((2 * k + laneHi2) ^ s7) << 3;
        return *(const bf16x8*)(&sAp[b * 16384 + row * 64 + up]);
    };
    auto ldb = [&](int b, int nt, int k) -> bf16x8 {
        const int row = wc * 64 + nt * 32 + lane31;
        const int up  = ((2 * k + laneHi2) ^ s7) << 3;
        return *(const bf16x8*)(&sBp[b * 16384 + row * 64 + up]);
    };

    f32x16 acc[4][2];
#pragma unroll
    for (int i = 0; i < 4; ++i)
#pragma unroll
        for (int j = 0; j < 2; ++j)
#pragma unroll
            for (int e = 0; e < 16; ++e) acc[i][j][e] = 0.f;

    bf16x8 af0, af1, af2, af3;
    bf16x8 bf00, bf01, bf02, bf03, bf10, bf11, bf12, bf13;

    // --- prologue (unchanged slots) ---
    stageA(0, 0, 0); stageA(0, 0, 1);
    stageB(0, 0, 0); stageB(0, 0, 1);
    stageB(1, 1, 0); stageB(1, 1, 1);
    VMW4;
    BARR;

    const int niter = K >> 7;
    for (int i = 0; i < niter; ++i) {
        const bool nlast = (i + 1 < niter);
        const int kO  = 2 * i + 1;
        const int kN  = 2 * i + 2;
        const int kN1 = 2 * i + 3;
        PHASE(0, 0, stageA(1, kO, 0), ((void)0));
        PHASE(0, 1, stageA(1, kO, 1), ((void)0));
        PHASE(0, 2, if (nlast) stageB(0, kN, 0), ((void)0));
        PHASE(0, 3, if (nlast) stageB(0, kN, 1),
              if (nlast) { VMW4; } else { VMW0; });
        PHASE(1, 0, if (nlast) stageA(0, kN, 0), ((void)0));
        PHASE(1, 1, if (nlast) stageA(0, kN, 1), ((void)0));
        PHASE(1, 2, if (nlast) stageB(1, kN1, 0), ((void)0));
        PHASE(1, 3, if (nlast) stageB(1, kN1, 1),
              if (nlast) { VMW4; });
    }

    // 32x32 C/D layout: col = lane&31, row = (r&3) + 8*(r>>2) + 4*(lane>>5)
    if (EPI == 0) {
        // LDS-staged coalesced bf16 epilogue (gelu); sC[256][256] bf16 with
        // bank XOR-swizzle (bits [6:5] ^= row>>2). Readback sweep unchanged.
        bf16_t* sC = (bf16_t*)smem;
#pragma unroll
        for (int nt = 0; nt < 2; ++nt) {
            const int colL = wc * 64 + nt * 32 + lane31;
            const float bv = bias[bn * 256 + colL];
#pragma unroll
            for (int mt = 0; mt < 4; ++mt) {
#pragma unroll
                for (int r = 0; r < 16; ++r) {
                    const int rowL = wr * 128 + mt * 32 + (r & 3) + 8 * (r >> 2)
                                     + 4 * laneHi2;
                    float v = acc[mt][nt][r] + bv;
                    int byte = (rowL << 9) + (colL << 1);
                    byte ^= ((rowL >> 2) & 3) << 5;
                    *(bf16_t*)((char*)sC + byte) = (bf16_t)gelu_f(v);
                }
            }
        }
        LGKM0;
        BARR;
        bf16_t* Cb = (bf16_t*)Cout;
        const size_t rb = (size_t)bm * 256, cb = (size_t)bn * 256;
#pragma unroll
        for (int s = 0; s < 16; ++s) {
            const int row = s * 16 + (tid >> 5);
            int byte = (row << 9) + ((tid & 31) << 4);
            byte ^= ((row >> 2) & 3) << 5;
            u32x4 v = *(const u32x4*)((char*)sC + byte);
            __builtin_nontemporal_store(
                v, (u32x4*)(&Cb[(rb + row) * N + cb + ((tid & 31) << 3)]));
        }
    } else {
        // direct f32 NT epilogue: 32 lanes x 4B = 128-B contiguous per row
        float* Cf = (float*)Cout;
#pragma unroll
        for (int nt = 0; nt < 2; ++nt) {
            const int col = bn * 256 + wc * 64 + nt * 32 + lane31;
            const float bv = bias[col];
#pragma unroll
            for (int mt = 0; mt < 4; ++mt) {
#pragma unroll
                for (int r = 0; r < 16; ++r) {
                    const int row = bm * 256 + wr * 128 + mt * 32 + (r & 3)
                                    + 8 * (r >> 2) + 4 * laneHi2;
                    __builtin_nontemporal_store(acc[mt][nt][r] + bv,
                                                &Cf[(size_t)row * N + col]);
                }
            }
        }
    }
}

// ---------------------------------------------------------------------------
extern "C" void kernel_launch(void* const* d_in, const int* in_sizes, int n_in,
                              void* d_out, int out_size, void* d_ws, size_t ws_size,
                              hipStream_t stream) {
    const float* inputs = (const float*)d_in[0];
    const float* up_w   = (const float*)d_in[1];
    const float* up_b   = (const float*)d_in[2];
    const float* dn_w   = (const float*)d_in[3];
    const float* dn_b   = (const float*)d_in[4];
    float* out = (float*)d_out;

    const int D = in_sizes[4];            // 2048
    const int F = in_sizes[2];            // 8192
    const int M = in_sizes[0] / D;        // 8192 (B*S)

    size_t r0_bytes = (size_t)(M > F ? M : F) * D * 2;
    char* ws = (char*)d_ws;
    bf16_t* in_bf = (bf16_t*)ws;                                       // M x D
    bf16_t* wup_t = (bf16_t*)(ws + r0_bytes);                          // F x D
    bf16_t* mid   = (bf16_t*)(ws + r0_bytes + (size_t)F * D * 2);      // M x F
    bf16_t* wdn_t = (bf16_t*)(ws + r0_bytes + (size_t)F * D * 2 + (size_t)M * F * 2); // D x F

    // 1) fused prep: cvt + quantize-up + quantize-down
    int ncvt = M * D;
    int cvtB = ncvt / (8 * 256);
    int qupB = ((D / 32) * F + 255) / 256;
    int qdnB = ((F / 32) * D + 255) / 256;
    prep_kernel<<<cvtB + qupB + qdnB, 256, 0, stream>>>(
        inputs, in_bf, ncvt, cvtB,
        up_w, wup_t, D, F, qupB,
        dn_w, wdn_t, F, D);

    // 2) GEMM1: mid = gelu(in @ W_up + b_up)   (4-round MAP1, proven best)
    gemm_kernel<0, 1><<<(M / 256) * (F / 256), 512, 0, stream>>>(
        in_bf, wup_t, up_b, (void*)mid, M, F, D);

    // 3) GEMM2: out = mid @ W_dn + b_dn
    gemm_kernel<1, 0><<<(M / 256) * (D / 256), 512, 0, stream>>>(
        mid, wdn_t, dn_b, (void*)out, M, D, F);
    (void)ws_size; (void)n_in; (void)out_size;
}

// Round 11
// 536.449 us; speedup vs baseline: 1.0990x; 1.0990x over previous
//
#include <hip/hip_runtime.h>
#include <hip/hip_bf16.h>

typedef __bf16 bf16_t;
typedef __attribute__((ext_vector_type(8))) __bf16 bf16x8;
typedef __attribute__((ext_vector_type(4))) float f32x4;
typedef __attribute__((ext_vector_type(4))) unsigned int u32x4;

// ---------------------------------------------------------------------------
// PACKED OPERAND LAYOUT: [rowTile][kTile][256 rows][64 elems], and within a
// row r the 8-elem unit u is stored at position u ^ (r&7). This is exactly
// the LDS image the GEMM wants, so staging is a flat contiguous copy
// (per-lane src = base + lane*16B) and fragment ds_reads are unchanged.
// Motivation: GEMM1's strided 8-rows-at-4KB gathers ran ~2x slower per
// staging instruction than GEMM2's (persistent-G1 352us vs G2 150us at equal
// iteration counts); linear staging removes the stride pathology entirely.
// ---------------------------------------------------------------------------
__device__ __forceinline__ void gload_lds16(const bf16_t* g, bf16_t* l) {
    __builtin_amdgcn_global_load_lds(
        (const __attribute__((address_space(1))) void*)g,
        (__attribute__((address_space(3))) void*)l,
        16, 0, 0);
}

__device__ __forceinline__ float gelu_f(float v) {
    float u = 0.7978845608028654f * (v + 0.044715f * v * v * v);
    float e = __expf(-2.f * u);
    float t = __fdividef(1.f - e, 1.f + e);   // tanh(u)
    return 0.5f * v * (1.f + t);
}

// ---------------------------------------------------------------------------
// MXFP4 quantize one (32-block b, column n) -> 32 dequantized bf16 written
// into the PACKED transposed operand (rows = n, k = b*32..b*32+31).
__device__ __forceinline__ void quant_one(const float* __restrict__ w,
                                          bf16_t* __restrict__ wt,
                                          int K, int N, int tix) {
    int n = tix % N;
    int b = tix / N;
    const float* src = w + (size_t)b * 32 * N + n;
    float v[32];
    float amax = 0.f;
#pragma unroll
    for (int i = 0; i < 32; ++i) {
        v[i] = __builtin_nontemporal_load(src + (size_t)i * N);
        amax = fmaxf(amax, fabsf(v[i]));
    }
    unsigned eb = (__float_as_uint(amax) >> 23) & 0xFF;
    float scale = __uint_as_float((eb - 2u) << 23);        // 2^(E-2)
    float inv   = __uint_as_float((256u - eb) << 23);      // 2^-(E-2)
    if (amax == 0.f) { scale = 0.f; inv = 0.f; }
    bf16_t dq[32];
#pragma unroll
    for (int i = 0; i < 32; ++i) {
        float x  = v[i] * inv;
        float ax = fabsf(x);
        float q = ax < 0.25f ? 0.0f : ax < 0.75f ? 0.5f : ax < 1.25f ? 1.0f :
                  ax < 1.75f ? 1.5f : ax < 2.5f  ? 2.0f : ax < 3.5f  ? 3.0f :
                  ax < 5.0f  ? 4.0f : 6.0f;
        float d = copysignf(q * scale, x);
        dq[i] = (bf16_t)d;
    }
    // packed dest: rowTile rt = n>>8, kTile kt = b>>1, row r = n&255,
    // units u = (b&1)*4 + j at swizzled position u ^ (r&7)
    const int r  = n & 255, rt = n >> 8, kt = b >> 1, ub = (b & 1) * 4;
    bf16_t* base = wt + (((size_t)rt * (K >> 6) + kt) << 14) + (r << 6);
#pragma unroll
    for (int j = 0; j < 4; ++j) {
        bf16x8 p;
#pragma unroll
        for (int t = 0; t < 8; ++t) p[t] = dq[j * 8 + t];
        *(bf16x8*)(base + (((ub + j) ^ (r & 7)) << 3)) = p;
    }
}

// ---------------------------------------------------------------------------
// Fused prep: [0,cvtB): inputs->bf16 packed; [cvtB,cvtB+qupB): quantize up;
// [cvtB+qupB,...): quantize down. All memory-bound, one launch.
__global__ void prep_kernel(const float* __restrict__ in, bf16_t* __restrict__ out,
                            int ncvt, int cvtB, int dLog,
                            const float* __restrict__ upw, bf16_t* __restrict__ upwt,
                            int upK, int upN, int qupB,
                            const float* __restrict__ dnw, bf16_t* __restrict__ dnwt,
                            int dnK, int dnN) {
    int bid = blockIdx.x;
    if (bid < cvtB) {
        int i = (bid * blockDim.x + threadIdx.x) << 3;
        if (i >= ncvt) return;
        const f32x4* p = (const f32x4*)(in + i);
        f32x4 a = __builtin_nontemporal_load(p);
        f32x4 b = __builtin_nontemporal_load(p + 1);
        bf16x8 o;
        o[0] = (bf16_t)a[0]; o[1] = (bf16_t)a[1]; o[2] = (bf16_t)a[2]; o[3] = (bf16_t)a[3];
        o[4] = (bf16_t)b[0]; o[5] = (bf16_t)b[1]; o[6] = (bf16_t)b[2]; o[7] = (bf16_t)b[3];
        // packed dest for row-major [M][D] activation
        const int row = i >> dLog, d = i & ((1 << dLog) - 1);
        const int r = row & 255, mt = row >> 8, dt = d >> 6, u = (d >> 3) & 7;
        size_t off = (((size_t)mt * (1 << (dLog - 6)) + dt) << 14) + (r << 6)
                     + ((u ^ (r & 7)) << 3);
        *(bf16x8*)(out + off) = o;
    } else if (bid < cvtB + qupB) {
        int tix = (bid - cvtB) * blockDim.x + threadIdx.x;
        if (tix >= (upK >> 5) * upN) return;
        quant_one(upw, upwt, upK, upN, tix);
    } else {
        int tix = (bid - cvtB - qupB) * blockDim.x + threadIdx.x;
        if (tix >= (dnK >> 5) * dnN) return;
        quant_one(dnw, dnwt, dnK, dnN, tix);
    }
}

// ---------------------------------------------------------------------------
// 256x256xBK=64 8-phase bf16 GEMM (16x16x32 MFMA; 32x32 regressed: bank
// conflicts 0 -> 2.5e7 and no gain). Packed-operand staging (linear copy).
#define VMW4  asm volatile("s_waitcnt vmcnt(4)" ::: "memory")
#define VMW0  asm volatile("s_waitcnt vmcnt(0)" ::: "memory")
#define BARR  asm volatile("s_barrier" ::: "memory")
#define LGKM0 asm volatile("s_waitcnt lgkmcnt(0)" ::: "memory")

#define MFMA_ROW(MI, A0, A1)                                                          \
    acc[MI][0] = __builtin_amdgcn_mfma_f32_16x16x32_bf16(A0, bf00, acc[MI][0],0,0,0); \
    acc[MI][0] = __builtin_amdgcn_mfma_f32_16x16x32_bf16(A1, bf01, acc[MI][0],0,0,0); \
    acc[MI][1] = __builtin_amdgcn_mfma_f32_16x16x32_bf16(A0, bf10, acc[MI][1],0,0,0); \
    acc[MI][1] = __builtin_amdgcn_mfma_f32_16x16x32_bf16(A1, bf11, acc[MI][1],0,0,0); \
    acc[MI][2] = __builtin_amdgcn_mfma_f32_16x16x32_bf16(A0, bf20, acc[MI][2],0,0,0); \
    acc[MI][2] = __builtin_amdgcn_mfma_f32_16x16x32_bf16(A1, bf21, acc[MI][2],0,0,0); \
    acc[MI][3] = __builtin_amdgcn_mfma_f32_16x16x32_bf16(A0, bf30, acc[MI][3],0,0,0); \
    acc[MI][3] = __builtin_amdgcn_mfma_f32_16x16x32_bf16(A1, bf31, acc[MI][3],0,0,0);

#define PHASE(BUF, P, STAGE_STMT, TAIL_STMT)                                          \
  {                                                                                   \
    af00 = lda(BUF, 2*(P),   0); af01 = lda(BUF, 2*(P),   1);                         \
    af10 = lda(BUF, 2*(P)+1, 0); af11 = lda(BUF, 2*(P)+1, 1);                         \
    if ((P) == 0) {                                                                   \
      bf00 = ldb(BUF,0,0); bf01 = ldb(BUF,0,1);                                       \
      bf10 = ldb(BUF,1,0); bf11 = ldb(BUF,1,1);                                       \
      bf20 = ldb(BUF,2,0); bf21 = ldb(BUF,2,1);                                       \
      bf30 = ldb(BUF,3,0); bf31 = ldb(BUF,3,1);                                       \
    }                                                                                 \
    STAGE_STMT;                                                                       \
    BARR;                                                                             \
    LGKM0;                                                                            \
    __builtin_amdgcn_s_setprio(1);                                                    \
    MFMA_ROW(2*(P),   af00, af01);                                                    \
    MFMA_ROW(2*(P)+1, af10, af11);                                                    \
    __builtin_amdgcn_s_setprio(0);                                                    \
    TAIL_STMT;                                                                        \
    BARR;                                                                             \
  }

// EPI 0: gelu+bias -> bf16 written to PACKED mid via LDS stage (coalesced 8KB
//        runs). EPI 1: bias -> f32 NT direct to linear output.
template <int EPI, int MAP>
__global__ __launch_bounds__(512, 2)
void gemm_kernel(const bf16_t* __restrict__ A, const bf16_t* __restrict__ Bt,
                 const float* __restrict__ bias, void* __restrict__ Cout,
                 int M, int N, int K) {
    __shared__ __align__(16) char smem[131072];
    bf16_t* sAp = (bf16_t*)smem;               // [2][256*64]
    bf16_t* sBp = (bf16_t*)(smem + 65536);     // [2][256*64]
    const int tid     = threadIdx.x;
    const int lane    = tid & 63;
    const int wv      = tid >> 6;
    const int wr      = wv >> 2;
    const int wc      = wv & 3;
    const int laneLow = lane & 15;
    const int laneHi  = lane >> 4;

    int bm, bn;
    const int bid = blockIdx.x;
    if (MAP == 1) {
        // hierarchical: per-XCD concurrent window = 4bm x 8bn supertile.
        const int xcd = bid & 7;
        const int l   = bid >> 3;
        const int r   = l >> 5;
        const int u   = l & 31;
        bm = r * 8 + ((xcd >> 2) << 2) + (u >> 3);
        bn = ((xcd & 3) << 3) + (u & 7);
    } else {
        const int ntn = N >> 8;
        const int nwg = gridDim.x;
        int wg  = (bid & 7) * (nwg >> 3) + (bid >> 3);
        bm = wg / ntn; bn = wg % ntn;
    }

    const int kT = K >> 6;   // k-tiles per operand row-tile

    // --- staging: FLAT copy of packed 32KB tiles; per-lane src linear ---
    auto stageA = [&](int b, int kt, int h) {
        const bf16_t* s = A + (((size_t)bm * kT + kt) << 14)
                            + ((h * 128 + wv * 8) << 6) + lane * 8;
        gload_lds16(s,        &sAp[b * 16384 + (h * 128 + wv * 8) * 64]);
        gload_lds16(s + 4096, &sAp[b * 16384 + (h * 128 + 64 + wv * 8) * 64]);
    };
    auto stageB = [&](int b, int kt, int h) {
        const bf16_t* s = Bt + (((size_t)bn * kT + kt) << 14)
                             + ((h * 128 + wv * 8) << 6) + lane * 8;
        gload_lds16(s,        &sBp[b * 16384 + (h * 128 + wv * 8) * 64]);
        gload_lds16(s + 4096, &sBp[b * 16384 + (h * 128 + 64 + wv * 8) * 64]);
    };

    // --- fragment reads (unchanged; same LDS image, proven conflict-free) ---
    const int s7  = laneLow & 7;
    const int xk0 = ((laneHi) ^ s7) << 3;
    const int xk1 = ((4 + laneHi) ^ s7) << 3;
    const int aOffBase = (wr * 128 + laneLow) * 64;
    const int bOffBase = (wc * 64 + laneLow) * 64;
    auto lda = [&](int b, int m, int ks) -> bf16x8 {
        return *(const bf16x8*)(&sAp[b * 16384 + aOffBase + m * 1024 + (ks ? xk1 : xk0)]);
    };
    auto ldb = [&](int b, int n2, int ks) -> bf16x8 {
        return *(const bf16x8*)(&sBp[b * 16384 + bOffBase + n2 * 1024 + (ks ? xk1 : xk0)]);
    };

    f32x4 acc[8][4];
#pragma unroll
    for (int i = 0; i < 8; ++i)
#pragma unroll
        for (int j = 0; j < 4; ++j) acc[i][j] = (f32x4){0.f, 0.f, 0.f, 0.f};

    bf16x8 af00, af01, af10, af11;
    bf16x8 bf00, bf01, bf10, bf11, bf20, bf21, bf30, bf31;

    stageA(0, 0, 0); stageA(0, 0, 1);
    stageB(0, 0, 0); stageB(0, 0, 1);
    stageB(1, 1, 0); stageB(1, 1, 1);
    VMW4;
    BARR;

    const int niter = kT >> 1;
    for (int i = 0; i < niter; ++i) {
        const bool nlast = (i + 1 < niter);
        const int kO  = 2 * i + 1;
        const int kN  = 2 * i + 2;
        const int kN1 = 2 * i + 3;
        PHASE(0, 0, stageA(1, kO, 0), ((void)0));
        PHASE(0, 1, stageA(1, kO, 1), ((void)0));
        PHASE(0, 2, if (nlast) stageB(0, kN, 0), ((void)0));
        PHASE(0, 3, if (nlast) stageB(0, kN, 1),
              if (nlast) { VMW4; } else { VMW0; });
        PHASE(1, 0, if (nlast) stageA(0, kN, 0), ((void)0));
        PHASE(1, 1, if (nlast) stageA(0, kN, 1), ((void)0));
        PHASE(1, 2, if (nlast) stageB(1, kN1, 0), ((void)0));
        PHASE(1, 3, if (nlast) stageB(1, kN1, 1),
              if (nlast) { VMW4; });
    }

    if (EPI == 0) {
        // LDS-staged epilogue producing PACKED mid. sC holds the 4 packed
        // [256][64] subtiles (+ bank XOR on byte bits[6:5] by rowL>>2).
        char* sC = smem;
#pragma unroll
        for (int n = 0; n < 4; ++n) {
            const int colL = wc * 64 + n * 16 + laneLow;
            const float bv = bias[bn * 256 + colL];
            const int u6   = (colL >> 3) & 7;
#pragma unroll
            for (int m = 0; m < 8; ++m) {
#pragma unroll
                for (int j = 0; j < 4; ++j) {
                    const int rowL = wr * 128 + m * 16 + (laneHi << 2) + j;
                    float v = acc[m][n][j] + bv;
                    int byte = ((colL >> 6) << 15) + (rowL << 7)
                             + ((u6 ^ (rowL & 7)) << 4) + ((colL & 7) << 1);
                    byte ^= ((rowL >> 2) & 3) << 5;
                    *(bf16_t*)(sC + byte) = (bf16_t)gelu_f(v);
                }
            }
        }
        LGKM0;
        BARR;
        // linear readback (un-XOR banks) -> NT store, 8KB contiguous runs
        char* dst = (char*)Cout + (((size_t)bm * (N >> 6) + bn * 4) << 15);
#pragma unroll
        for (int s = 0; s < 16; ++s) {
            int lin = s * 8192 + tid * 16;
            int row = (lin >> 7) & 255;
            int rb  = lin ^ (((row >> 2) & 3) << 5);
            u32x4 v = *(const u32x4*)(sC + rb);
            __builtin_nontemporal_store(v, (u32x4*)(dst + lin));
        }
    } else {
        // direct f32 NT epilogue to the required linear output
        const int r0 = bm * 256 + wr * 128 + (laneHi << 2);
        const int c0 = bn * 256 + wc * 64 + laneLow;
        float* Cf = (float*)Cout;
#pragma unroll
        for (int n = 0; n < 4; ++n) {
            const int col = c0 + n * 16;
            const float bv = bias[col];
#pragma unroll
            for (int m = 0; m < 8; ++m) {
#pragma unroll
                for (int j = 0; j < 4; ++j) {
                    const int row = r0 + m * 16 + j;
                    __builtin_nontemporal_store(acc[m][n][j] + bv,
                                                &Cf[(size_t)row * N + col]);
                }
            }
        }
    }
}

// ---------------------------------------------------------------------------
extern "C" void kernel_launch(void* const* d_in, const int* in_sizes, int n_in,
                              void* d_out, int out_size, void* d_ws, size_t ws_size,
                              hipStream_t stream) {
    const float* inputs = (const float*)d_in[0];
    const float* up_w   = (const float*)d_in[1];
    const float* up_b   = (const float*)d_in[2];
    const float* dn_w   = (const float*)d_in[3];
    const float* dn_b   = (const float*)d_in[4];
    float* out = (float*)d_out;

    const int D = in_sizes[4];            // 2048
    const int F = in_sizes[2];            // 8192
    const int M = in_sizes[0] / D;        // 8192 (B*S)
    const int dLog = 31 - __builtin_clz((unsigned)D);

    size_t r0_bytes = (size_t)(M > F ? M : F) * D * 2;
    char* ws = (char*)d_ws;
    bf16_t* in_bf = (bf16_t*)ws;                                       // packed M x D
    bf16_t* wup_t = (bf16_t*)(ws + r0_bytes);                          // packed F x D
    bf16_t* mid   = (bf16_t*)(ws + r0_bytes + (size_t)F * D * 2);      // packed M x F
    bf16_t* wdn_t = (bf16_t*)(ws + r0_bytes + (size_t)F * D * 2 + (size_t)M * F * 2); // packed D x F

    // 1) fused prep: cvt + quantize-up + quantize-down (all packed outputs)
    int ncvt = M * D;
    int cvtB = ncvt / (8 * 256);
    int qupB = ((D / 32) * F + 255) / 256;
    int qdnB = ((F / 32) * D + 255) / 256;
    prep_kernel<<<cvtB + qupB + qdnB, 256, 0, stream>>>(
        inputs, in_bf, ncvt, cvtB, dLog,
        up_w, wup_t, D, F, qupB,
        dn_w, wdn_t, F, D);

    // 2) GEMM1: mid = gelu(in @ W_up + b_up)   (4-round MAP1, 16x16 MFMA)
    gemm_kernel<0, 1><<<(M / 256) * (F / 256), 512, 0, stream>>>(
        in_bf, wup_t, up_b, (void*)mid, M, F, D);

    // 3) GEMM2: out = mid @ W_dn + b_dn
    gemm_kernel<1, 0><<<(M / 256) * (D / 256), 512, 0, stream>>>(
        mid, wdn_t, dn_b, (void*)out, M, D, F);
    (void)ws_size; (void)n_in; (void)out_size;
}

// Round 12
// 529.868 us; speedup vs baseline: 1.1126x; 1.0124x over previous
//
#include <hip/hip_runtime.h>
#include <hip/hip_bf16.h>

typedef __bf16 bf16_t;
typedef __attribute__((ext_vector_type(8))) __bf16 bf16x8;
typedef __attribute__((ext_vector_type(4))) float f32x4;
typedef __attribute__((ext_vector_type(4))) unsigned int u32x4;

// ---------------------------------------------------------------------------
// PACKED OPERAND LAYOUT (unchanged from round 11): [rowTile][kTile][256][64],
// unit u of row r stored at u ^ (r&7). Staging is a flat linear copy.
// ---------------------------------------------------------------------------
__device__ __forceinline__ void gload_lds16(const bf16_t* g, bf16_t* l) {
    __builtin_amdgcn_global_load_lds(
        (const __attribute__((address_space(1))) void*)g,
        (__attribute__((address_space(3))) void*)l,
        16, 0, 0);
}

__device__ __forceinline__ float gelu_f(float v) {
    float u = 0.7978845608028654f * (v + 0.044715f * v * v * v);
    float e = __expf(-2.f * u);
    float t = __fdividef(1.f - e, 1.f + e);   // tanh(u)
    return 0.5f * v * (1.f + t);
}

// ---------------------------------------------------------------------------
__device__ __forceinline__ void quant_one(const float* __restrict__ w,
                                          bf16_t* __restrict__ wt,
                                          int K, int N, int tix) {
    int n = tix % N;
    int b = tix / N;
    const float* src = w + (size_t)b * 32 * N + n;
    float v[32];
    float amax = 0.f;
#pragma unroll
    for (int i = 0; i < 32; ++i) {
        v[i] = __builtin_nontemporal_load(src + (size_t)i * N);
        amax = fmaxf(amax, fabsf(v[i]));
    }
    unsigned eb = (__float_as_uint(amax) >> 23) & 0xFF;
    float scale = __uint_as_float((eb - 2u) << 23);        // 2^(E-2)
    float inv   = __uint_as_float((256u - eb) << 23);      // 2^-(E-2)
    if (amax == 0.f) { scale = 0.f; inv = 0.f; }
    bf16_t dq[32];
#pragma unroll
    for (int i = 0; i < 32; ++i) {
        float x  = v[i] * inv;
        float ax = fabsf(x);
        float q = ax < 0.25f ? 0.0f : ax < 0.75f ? 0.5f : ax < 1.25f ? 1.0f :
                  ax < 1.75f ? 1.5f : ax < 2.5f  ? 2.0f : ax < 3.5f  ? 3.0f :
                  ax < 5.0f  ? 4.0f : 6.0f;
        float d = copysignf(q * scale, x);
        dq[i] = (bf16_t)d;
    }
    const int r  = n & 255, rt = n >> 8, kt = b >> 1, ub = (b & 1) * 4;
    bf16_t* base = wt + (((size_t)rt * (K >> 6) + kt) << 14) + (r << 6);
#pragma unroll
    for (int j = 0; j < 4; ++j) {
        bf16x8 p;
#pragma unroll
        for (int t = 0; t < 8; ++t) p[t] = dq[j * 8 + t];
        *(bf16x8*)(base + (((ub + j) ^ (r & 7)) << 3)) = p;
    }
}

// ---------------------------------------------------------------------------
__global__ void prep_kernel(const float* __restrict__ in, bf16_t* __restrict__ out,
                            int ncvt, int cvtB, int dLog,
                            const float* __restrict__ upw, bf16_t* __restrict__ upwt,
                            int upK, int upN, int qupB,
                            const float* __restrict__ dnw, bf16_t* __restrict__ dnwt,
                            int dnK, int dnN) {
    int bid = blockIdx.x;
    if (bid < cvtB) {
        int i = (bid * blockDim.x + threadIdx.x) << 3;
        if (i >= ncvt) return;
        const f32x4* p = (const f32x4*)(in + i);
        f32x4 a = __builtin_nontemporal_load(p);
        f32x4 b = __builtin_nontemporal_load(p + 1);
        bf16x8 o;
        o[0] = (bf16_t)a[0]; o[1] = (bf16_t)a[1]; o[2] = (bf16_t)a[2]; o[3] = (bf16_t)a[3];
        o[4] = (bf16_t)b[0]; o[5] = (bf16_t)b[1]; o[6] = (bf16_t)b[2]; o[7] = (bf16_t)b[3];
        const int row = i >> dLog, d = i & ((1 << dLog) - 1);
        const int r = row & 255, mt = row >> 8, dt = d >> 6, u = (d >> 3) & 7;
        size_t off = (((size_t)mt * (1 << (dLog - 6)) + dt) << 14) + (r << 6)
                     + ((u ^ (r & 7)) << 3);
        *(bf16x8*)(out + off) = o;
    } else if (bid < cvtB + qupB) {
        int tix = (bid - cvtB) * blockDim.x + threadIdx.x;
        if (tix >= (upK >> 5) * upN) return;
        quant_one(upw, upwt, upK, upN, tix);
    } else {
        int tix = (bid - cvtB - qupB) * blockDim.x + threadIdx.x;
        if (tix >= (dnK >> 5) * dnN) return;
        quant_one(dnw, dnwt, dnK, dnN, tix);
    }
}

// ---------------------------------------------------------------------------
#define VMW4  asm volatile("s_waitcnt vmcnt(4)" ::: "memory")
#define VMW0  asm volatile("s_waitcnt vmcnt(0)" ::: "memory")
#define BARR  asm volatile("s_barrier" ::: "memory")
#define LGKM0 asm volatile("s_waitcnt lgkmcnt(0)" ::: "memory")

// ---------------------------------------------------------------------------
// GEMM1: 256x128 tile, BK=64, SINGLE-buffered 48KB LDS, 2 blocks/CU.
// Rationale: GEMM1 is invariant at ~340us across all data-side fixes; at
// 1 block/CU (128KB LDS) its stall/boundary exposure has nothing to overlap.
// This variant trades intra-block pipelining for INTER-block overlap (m114):
// while one block waits on staging, the co-resident block's waves issue MFMA.
// acc[4][4]=64 VGPR; __launch_bounds__(512,4) caps at 128 VGPR for 2 blocks.
__global__ __launch_bounds__(512, 4)
void gemm1_kernel(const bf16_t* __restrict__ A, const bf16_t* __restrict__ Bt,
                  const float* __restrict__ bias, bf16_t* __restrict__ C,
                  int M, int N, int K) {
    __shared__ __align__(16) char smem[65536];   // loop: sA 32K + sB 16K; epi: 64K
    bf16_t* sAp = (bf16_t*)smem;                  // [256][64]
    bf16_t* sBp = (bf16_t*)(smem + 32768);        // [128][64]
    const int tid     = threadIdx.x;
    const int lane    = tid & 63;
    const int wv      = tid >> 6;          // 0..7
    const int wr      = wv >> 1;           // 0..3 (64-row strips)
    const int wc      = wv & 1;            // 0..1 (64-col strips)
    const int laneLow = lane & 15;
    const int laneHi  = lane >> 4;

    // bijective map, per-XCD window = 8bm x 4bn (B reused x8, A x4 in L2)
    const int bid = blockIdx.x;
    const int xcd = bid & 7, l = bid >> 3, r = l >> 5, u = l & 31;
    const int bm = ((xcd & 1) << 3) + (u >> 2) + ((r & 1) << 4);   // 0..31
    const int bn = ((xcd >> 1) << 2) + (u & 3) + ((r >> 1) << 4);  // 0..63

    const int kT = K >> 6;                 // 32 k-tiles
    const int rtB = bn >> 1;               // packed B row-tile
    const size_t bHalf = (size_t)(bn & 1) << 13;  // 128 rows x 64 elems

    // --- staging: flat linear copies of packed tiles ---
    auto stageA = [&](int kt) {
        const bf16_t* s = A + (((size_t)bm * kT + kt) << 14)
                            + ((wv * 8) << 6) + lane * 8;
#pragma unroll
        for (int h = 0; h < 2; ++h) {
            gload_lds16(s + h * 8192,        &sAp[(h * 128 + wv * 8) * 64]);
            gload_lds16(s + h * 8192 + 4096, &sAp[(h * 128 + 64 + wv * 8) * 64]);
        }
    };
    auto stageB = [&](int kt) {
        const bf16_t* s = Bt + (((size_t)rtB * kT + kt) << 14) + bHalf
                             + ((wv * 8) << 6) + lane * 8;
        gload_lds16(s,        &sBp[(wv * 8) * 64]);
        gload_lds16(s + 4096, &sBp[(64 + wv * 8) * 64]);
    };

    // --- fragment reads (same XOR image, conflict-free) ---
    const int s7  = laneLow & 7;
    const int xk0 = ((laneHi) ^ s7) << 3;
    const int xk1 = ((4 + laneHi) ^ s7) << 3;
    const int aOffBase = (wr * 64 + laneLow) * 64;
    const int bOffBase = (wc * 64 + laneLow) * 64;

    f32x4 acc[4][4];
#pragma unroll
    for (int i = 0; i < 4; ++i)
#pragma unroll
        for (int j = 0; j < 4; ++j) acc[i][j] = (f32x4){0.f, 0.f, 0.f, 0.f};

#pragma unroll 1
    for (int kt = 0; kt < kT; ++kt) {
        stageA(kt); stageB(kt);
        VMW0;
        BARR;
        __builtin_amdgcn_s_setprio(1);
#pragma unroll
        for (int ks = 0; ks < 2; ++ks) {
            const int xk = ks ? xk1 : xk0;
            bf16x8 b0 = *(const bf16x8*)(&sBp[bOffBase + 0 * 1024 + xk]);
            bf16x8 b1 = *(const bf16x8*)(&sBp[bOffBase + 1 * 1024 + xk]);
            bf16x8 b2 = *(const bf16x8*)(&sBp[bOffBase + 2 * 1024 + xk]);
            bf16x8 b3 = *(const bf16x8*)(&sBp[bOffBase + 3 * 1024 + xk]);
#pragma unroll
            for (int m = 0; m < 4; ++m) {
                bf16x8 a = *(const bf16x8*)(&sAp[aOffBase + m * 1024 + xk]);
                acc[m][0] = __builtin_amdgcn_mfma_f32_16x16x32_bf16(a, b0, acc[m][0], 0, 0, 0);
                acc[m][1] = __builtin_amdgcn_mfma_f32_16x16x32_bf16(a, b1, acc[m][1], 0, 0, 0);
                acc[m][2] = __builtin_amdgcn_mfma_f32_16x16x32_bf16(a, b2, acc[m][2], 0, 0, 0);
                acc[m][3] = __builtin_amdgcn_mfma_f32_16x16x32_bf16(a, b3, acc[m][3], 0, 0, 0);
            }
        }
        __builtin_amdgcn_s_setprio(0);
        BARR;     // all waves done reading before next stage overwrites
    }

    // --- epilogue: full 256x128 bf16 tile staged in 64KB LDS (packed-mid
    //     image + bank XOR), then linear NT dwordx4 readback (8KB runs). ---
    char* sC = smem;
#pragma unroll
    for (int n = 0; n < 4; ++n) {
        const int colL = wc * 64 + n * 16 + laneLow;
        const float bv = bias[bn * 128 + colL];
        const int u6   = (colL >> 3) & 7;
#pragma unroll
        for (int m = 0; m < 4; ++m) {
#pragma unroll
            for (int j = 0; j < 4; ++j) {
                const int rowL = wr * 64 + m * 16 + (laneHi << 2) + j;
                float v = acc[m][n][j] + bv;
                int byte = ((colL >> 6) << 15) + (rowL << 7)
                         + ((u6 ^ (rowL & 7)) << 4) + ((colL & 7) << 1);
                byte ^= ((rowL >> 2) & 3) << 5;
                *(bf16_t*)(sC + byte) = (bf16_t)gelu_f(v);
            }
        }
    }
    LGKM0;
    BARR;
    char* dst = (char*)C + (((size_t)bm * (N >> 6) + bn * 2) << 15);
#pragma unroll
    for (int s = 0; s < 8; ++s) {
        int lin = s * 8192 + tid * 16;
        int row = (lin >> 7) & 255;
        int rb  = lin ^ (((row >> 2) & 3) << 5);
        u32x4 v = *(const u32x4*)(sC + rb);
        __builtin_nontemporal_store(v, (u32x4*)(dst + lin));
    }
}

// ---------------------------------------------------------------------------
// GEMM2 (unchanged control): 256x256, BK=64, 8-phase double-buffered,
// counted vmcnt, f32 NT direct epilogue. Consumes packed A/B.
#define MFMA_ROW(MI, A0, A1)                                                          \
    acc[MI][0] = __builtin_amdgcn_mfma_f32_16x16x32_bf16(A0, bf00, acc[MI][0],0,0,0); \
    acc[MI][0] = __builtin_amdgcn_mfma_f32_16x16x32_bf16(A1, bf01, acc[MI][0],0,0,0); \
    acc[MI][1] = __builtin_amdgcn_mfma_f32_16x16x32_bf16(A0, bf10, acc[MI][1],0,0,0); \
    acc[MI][1] = __builtin_amdgcn_mfma_f32_16x16x32_bf16(A1, bf11, acc[MI][1],0,0,0); \
    acc[MI][2] = __builtin_amdgcn_mfma_f32_16x16x32_bf16(A0, bf20, acc[MI][2],0,0,0); \
    acc[MI][2] = __builtin_amdgcn_mfma_f32_16x16x32_bf16(A1, bf21, acc[MI][2],0,0,0); \
    acc[MI][3] = __builtin_amdgcn_mfma_f32_16x16x32_bf16(A0, bf30, acc[MI][3],0,0,0); \
    acc[MI][3] = __builtin_amdgcn_mfma_f32_16x16x32_bf16(A1, bf31, acc[MI][3],0,0,0);

#define PHASE(BUF, P, STAGE_STMT, TAIL_STMT)                                          \
  {                                                                                   \
    af00 = lda(BUF, 2*(P),   0); af01 = lda(BUF, 2*(P),   1);                         \
    af10 = lda(BUF, 2*(P)+1, 0); af11 = lda(BUF, 2*(P)+1, 1);                         \
    if ((P) == 0) {                                                                   \
      bf00 = ldb(BUF,0,0); bf01 = ldb(BUF,0,1);                                       \
      bf10 = ldb(BUF,1,0); bf11 = ldb(BUF,1,1);                                       \
      bf20 = ldb(BUF,2,0); bf21 = ldb(BUF,2,1);                                       \
      bf30 = ldb(BUF,3,0); bf31 = ldb(BUF,3,1);                                       \
    }                                                                                 \
    STAGE_STMT;                                                                       \
    BARR;                                                                             \
    LGKM0;                                                                            \
    __builtin_amdgcn_s_setprio(1);                                                    \
    MFMA_ROW(2*(P),   af00, af01);                                                    \
    MFMA_ROW(2*(P)+1, af10, af11);                                                    \
    __builtin_amdgcn_s_setprio(0);                                                    \
    TAIL_STMT;                                                                        \
    BARR;                                                                             \
  }

__global__ __launch_bounds__(512, 2)
void gemm2_kernel(const bf16_t* __restrict__ A, const bf16_t* __restrict__ Bt,
                  const float* __restrict__ bias, float* __restrict__ Cf,
                  int M, int N, int K) {
    __shared__ __align__(16) char smem[131072];
    bf16_t* sAp = (bf16_t*)smem;
    bf16_t* sBp = (bf16_t*)(smem + 65536);
    const int tid     = threadIdx.x;
    const int lane    = tid & 63;
    const int wv      = tid >> 6;
    const int wr      = wv >> 2;
    const int wc      = wv & 3;
    const int laneLow = lane & 15;
    const int laneHi  = lane >> 4;

    const int ntn = N >> 8;
    const int nwg = gridDim.x;
    const int bid = blockIdx.x;
    int wg  = (bid & 7) * (nwg >> 3) + (bid >> 3);
    const int bm = wg / ntn, bn = wg % ntn;

    const int kT = K >> 6;

    auto stageA = [&](int b, int kt, int h) {
        const bf16_t* s = A + (((size_t)bm * kT + kt) << 14)
                            + ((h * 128 + wv * 8) << 6) + lane * 8;
        gload_lds16(s,        &sAp[b * 16384 + (h * 128 + wv * 8) * 64]);
        gload_lds16(s + 4096, &sAp[b * 16384 + (h * 128 + 64 + wv * 8) * 64]);
    };
    auto stageB = [&](int b, int kt, int h) {
        const bf16_t* s = Bt + (((size_t)bn * kT + kt) << 14)
                             + ((h * 128 + wv * 8) << 6) + lane * 8;
        gload_lds16(s,        &sBp[b * 16384 + (h * 128 + wv * 8) * 64]);
        gload_lds16(s + 4096, &sBp[b * 16384 + (h * 128 + 64 + wv * 8) * 64]);
    };

    const int s7  = laneLow & 7;
    const int xk0 = ((laneHi) ^ s7) << 3;
    const int xk1 = ((4 + laneHi) ^ s7) << 3;
    const int aOffBase = (wr * 128 + laneLow) * 64;
    const int bOffBase = (wc * 64 + laneLow) * 64;
    auto lda = [&](int b, int m, int ks) -> bf16x8 {
        return *(const bf16x8*)(&sAp[b * 16384 + aOffBase + m * 1024 + (ks ? xk1 : xk0)]);
    };
    auto ldb = [&](int b, int n2, int ks) -> bf16x8 {
        return *(const bf16x8*)(&sBp[b * 16384 + bOffBase + n2 * 1024 + (ks ? xk1 : xk0)]);
    };

    f32x4 acc[8][4];
#pragma unroll
    for (int i = 0; i < 8; ++i)
#pragma unroll
        for (int j = 0; j < 4; ++j) acc[i][j] = (f32x4){0.f, 0.f, 0.f, 0.f};

    bf16x8 af00, af01, af10, af11;
    bf16x8 bf00, bf01, bf10, bf11, bf20, bf21, bf30, bf31;

    stageA(0, 0, 0); stageA(0, 0, 1);
    stageB(0, 0, 0); stageB(0, 0, 1);
    stageB(1, 1, 0); stageB(1, 1, 1);
    VMW4;
    BARR;

    const int niter = kT >> 1;
    for (int i = 0; i < niter; ++i) {
        const bool nlast = (i + 1 < niter);
        const int kO  = 2 * i + 1;
        const int kN  = 2 * i + 2;
        const int kN1 = 2 * i + 3;
        PHASE(0, 0, stageA(1, kO, 0), ((void)0));
        PHASE(0, 1, stageA(1, kO, 1), ((void)0));
        PHASE(0, 2, if (nlast) stageB(0, kN, 0), ((void)0));
        PHASE(0, 3, if (nlast) stageB(0, kN, 1),
              if (nlast) { VMW4; } else { VMW0; });
        PHASE(1, 0, if (nlast) stageA(0, kN, 0), ((void)0));
        PHASE(1, 1, if (nlast) stageA(0, kN, 1), ((void)0));
        PHASE(1, 2, if (nlast) stageB(1, kN1, 0), ((void)0));
        PHASE(1, 3, if (nlast) stageB(1, kN1, 1),
              if (nlast) { VMW4; });
    }

    const int r0 = bm * 256 + wr * 128 + (laneHi << 2);
    const int c0 = bn * 256 + wc * 64 + laneLow;
#pragma unroll
    for (int n = 0; n < 4; ++n) {
        const int col = c0 + n * 16;
        const float bv = bias[col];
#pragma unroll
        for (int m = 0; m < 8; ++m) {
#pragma unroll
            for (int j = 0; j < 4; ++j) {
                const int row = r0 + m * 16 + j;
                __builtin_nontemporal_store(acc[m][n][j] + bv,
                                            &Cf[(size_t)row * N + col]);
            }
        }
    }
}

// ---------------------------------------------------------------------------
extern "C" void kernel_launch(void* const* d_in, const int* in_sizes, int n_in,
                              void* d_out, int out_size, void* d_ws, size_t ws_size,
                              hipStream_t stream) {
    const float* inputs = (const float*)d_in[0];
    const float* up_w   = (const float*)d_in[1];
    const float* up_b   = (const float*)d_in[2];
    const float* dn_w   = (const float*)d_in[3];
    const float* dn_b   = (const float*)d_in[4];
    float* out = (float*)d_out;

    const int D = in_sizes[4];            // 2048
    const int F = in_sizes[2];            // 8192
    const int M = in_sizes[0] / D;        // 8192 (B*S)
    const int dLog = 31 - __builtin_clz((unsigned)D);

    size_t r0_bytes = (size_t)(M > F ? M : F) * D * 2;
    char* ws = (char*)d_ws;
    bf16_t* in_bf = (bf16_t*)ws;                                       // packed M x D
    bf16_t* wup_t = (bf16_t*)(ws + r0_bytes);                          // packed F x D
    bf16_t* mid   = (bf16_t*)(ws + r0_bytes + (size_t)F * D * 2);      // packed M x F
    bf16_t* wdn_t = (bf16_t*)(ws + r0_bytes + (size_t)F * D * 2 + (size_t)M * F * 2); // packed D x F

    // 1) fused prep: cvt + quantize-up + quantize-down (packed outputs)
    int ncvt = M * D;
    int cvtB = ncvt / (8 * 256);
    int qupB = ((D / 32) * F + 255) / 256;
    int qdnB = ((F / 32) * D + 255) / 256;
    prep_kernel<<<cvtB + qupB + qdnB, 256, 0, stream>>>(
        inputs, in_bf, ncvt, cvtB, dLog,
        up_w, wup_t, D, F, qupB,
        dn_w, wdn_t, F, D);

    // 2) GEMM1: mid = gelu(in @ W_up + b_up) -- 256x128 tile, 2 blocks/CU
    gemm1_kernel<<<(M / 256) * (F / 128), 512, 0, stream>>>(
        in_bf, wup_t, up_b, mid, M, F, D);

    // 3) GEMM2: out = mid @ W_dn + b_dn
    gemm2_kernel<<<(M / 256) * (D / 256), 512, 0, stream>>>(
        mid, wdn_t, dn_b, out, M, D, F);
    (void)ws_size; (void)n_in; (void)out_size;
}